// Round 1
// baseline (859.560 us; speedup 1.0000x reference)
//
#include <hip/hip_runtime.h>
#include <cmath>

// Problem constants
constexpr int Bn   = 64;
constexpr int Sn   = 8192;
constexpr int DDEC = 128;
constexpr int DENC = 128;
constexpr int Fn   = 16;
constexpr int Un   = 128;

__device__ __forceinline__ float fast_tanh(float x) {
    // tanh(x) = sign(x) * (1 - 2/(exp(2|x|)+1)); exp overflow -> rcp(inf)=0 -> t=1 (correct saturation)
    float ax = fabsf(x);
    float e  = __expf(2.0f * ax);
    float t  = 1.0f - 2.0f * __builtin_amdgcn_rcpf(e + 1.0f);
    return copysignf(t, x);
}

// Setup: qq[b][u] = dec[b]@W1[:,u] + W1_b[u] + W2_b[u]   (W2 bias folded in)
//        w2t[u][d] = W2[d][u]  (u-major so hot loop reads contiguous, wave-uniform rows)
__global__ void setup_kernel(const float* __restrict__ dec,
                             const float* __restrict__ W1,
                             const float* __restrict__ W1b,
                             const float* __restrict__ W2,
                             const float* __restrict__ W2b,
                             float* __restrict__ qq,
                             float* __restrict__ w2t) {
    int u = threadIdx.x;           // 128 threads
    int blk = blockIdx.x;
    if (blk < Bn) {
        int b = blk;
        float acc = W1b[u] + W2b[u];
        #pragma unroll 8
        for (int d = 0; d < DDEC; ++d)
            acc = fmaf(dec[b * DDEC + d], W1[d * Un + u], acc);
        qq[b * Un + u] = acc;
    } else {
        for (int d = 0; d < DENC; ++d)
            w2t[u * DENC + d] = W2[d * Un + u];
    }
}

// Main: per thread = one (b,s) row.
// logits[b][s] = 10*tanh( sum_u tanh(qq[b][u] + enc_row . w2t[u]) * V[u] + Vb ) - mask*1e9
__global__ __launch_bounds__(256, 3)
void score_kernel(const float* __restrict__ enc,    // [B,S,DENC]
                  const float* __restrict__ mask,   // [B,S]
                  const float* __restrict__ qq,     // [B,U]
                  const float* __restrict__ w2t,    // [U,DENC] u-major
                  const float* __restrict__ V,      // [U]
                  const float* __restrict__ Vb,     // [1]
                  float* __restrict__ logits) {     // [B,S]
    int row = blockIdx.x * 256 + threadIdx.x;       // 0..B*S-1
    int b = row >> 13;                              // S = 8192

    // Load this row's 512 B of enc into registers (line-granular per lane).
    const float4* erow = (const float4*)(enc + (size_t)row * DENC);
    float4 e[32];
    #pragma unroll
    for (int j = 0; j < 32; ++j) e[j] = erow[j];

    const float* qrow = qq + b * Un;
    float score = Vb[0];

    for (int u = 0; u < Un; ++u) {
        const float4* w = (const float4*)(w2t + u * DENC);  // wave-uniform -> s_load
        float k = qrow[u];
        #pragma unroll
        for (int j = 0; j < 32; ++j) {
            float4 wv = w[j];
            k = fmaf(e[j].x, wv.x, k);
            k = fmaf(e[j].y, wv.y, k);
            k = fmaf(e[j].z, wv.z, k);
            k = fmaf(e[j].w, wv.w, k);
        }
        score = fmaf(fast_tanh(k), V[u], score);
    }

    float logit = 10.0f * fast_tanh(score) - mask[row] * 1e9f;
    logits[row] = logit;
}

// Softmax + argmax + gather, one block per b.
__global__ __launch_bounds__(256)
void softmax_kernel(const float* __restrict__ logits,  // [B,S]
                    const float* __restrict__ enc_in,  // [B,S,F]
                    float* __restrict__ probs,         // [B,S]
                    float* __restrict__ out_idx,       // [B] (written as float)
                    float* __restrict__ out_gath) {    // [B,F]
    int b = blockIdx.x, tid = threadIdx.x;
    __shared__ float smax[256];
    __shared__ int   sidx[256];
    __shared__ float ssum[256];

    const float* lrow = logits + (size_t)b * Sn;

    // Pass 1: max + first-occurrence argmax
    float bestv = -INFINITY; int besti = 0x7fffffff;
    for (int s = tid; s < Sn; s += 256) {
        float v = lrow[s];
        if (v > bestv) { bestv = v; besti = s; }
    }
    smax[tid] = bestv; sidx[tid] = besti;
    __syncthreads();
    for (int off = 128; off > 0; off >>= 1) {
        if (tid < off) {
            float ov = smax[tid + off]; int oi = sidx[tid + off];
            if (ov > smax[tid] || (ov == smax[tid] && oi < sidx[tid])) {
                smax[tid] = ov; sidx[tid] = oi;
            }
        }
        __syncthreads();
    }
    float M = smax[0]; int I = sidx[0];

    // Pass 2: sum of exp
    float psum = 0.0f;
    for (int s = tid; s < Sn; s += 256) psum += __expf(lrow[s] - M);
    ssum[tid] = psum;
    __syncthreads();
    for (int off = 128; off > 0; off >>= 1) {
        if (tid < off) ssum[tid] += ssum[tid + off];
        __syncthreads();
    }
    float inv = 1.0f / ssum[0];

    // Pass 3: write probs
    for (int s = tid; s < Sn; s += 256)
        probs[(size_t)b * Sn + s] = __expf(lrow[s] - M) * inv;

    // Index (numeric value as float32) + gather
    if (tid == 0) out_idx[b] = (float)I;
    if (tid < Fn) out_gath[b * Fn + tid] = enc_in[((size_t)b * Sn + I) * Fn + tid];
}

extern "C" void kernel_launch(void* const* d_in, const int* in_sizes, int n_in,
                              void* d_out, int out_size, void* d_ws, size_t ws_size,
                              hipStream_t stream) {
    const float* dec    = (const float*)d_in[0];  // [B,1,DDEC]
    const float* enc_in = (const float*)d_in[1];  // [B,S,F]
    const float* enc    = (const float*)d_in[2];  // [B,S,DENC]
    const float* mask   = (const float*)d_in[3];  // [B,S]
    const float* W1     = (const float*)d_in[4];  // [DDEC,U]
    const float* W1b    = (const float*)d_in[5];  // [U]
    const float* W2     = (const float*)d_in[6];  // [DENC,U]
    const float* W2b    = (const float*)d_in[7];  // [U]
    const float* V      = (const float*)d_in[8];  // [U,1]
    const float* Vb     = (const float*)d_in[9];  // [1]

    float* qq  = (float*)d_ws;          // B*U floats
    float* w2t = qq + Bn * Un;          // U*DENC floats

    float* logits = (float*)d_out;                  // [B,S]
    float* probs  = logits + (size_t)Bn * Sn;       // [B,S]
    float* oidx   = probs + (size_t)Bn * Sn;        // [B]
    float* ogath  = oidx + Bn;                      // [B,F]

    setup_kernel<<<Bn + 1, 128, 0, stream>>>(dec, W1, W1b, W2, W2b, qq, w2t);
    score_kernel<<<(Bn * Sn) / 256, 256, 0, stream>>>(enc, mask, qq, w2t, V, Vb, logits);
    softmax_kernel<<<Bn, 256, 0, stream>>>(logits, enc_in, probs, oidx, ogath);
}

// Round 2
// 764.807 us; speedup vs baseline: 1.1239x; 1.1239x over previous
//
#include <hip/hip_runtime.h>
#include <cmath>

// Problem constants
constexpr int Bn   = 64;
constexpr int Sn   = 8192;
constexpr int DDEC = 128;
constexpr int DENC = 128;
constexpr int Fn   = 16;
constexpr int Un   = 128;

__device__ __forceinline__ float fast_tanh(float x) {
    // tanh(x) = sign(x) * (1 - 2/(exp(2|x|)+1)); exp overflow -> rcp(inf)=0 -> t=1 (correct saturation)
    float ax = fabsf(x);
    float e  = __expf(2.0f * ax);
    float t  = 1.0f - 2.0f * __builtin_amdgcn_rcpf(e + 1.0f);
    return copysignf(t, x);
}

// Setup: qq[b][u] = dec[b]@W1[:,u] + W1_b[u] + W2_b[u]   (W2 bias folded in)
//        w2t[u][d] = W2[d][u]  (u-major so hot loop reads wave-uniform rows -> s_load)
__global__ void setup_kernel(const float* __restrict__ dec,
                             const float* __restrict__ W1,
                             const float* __restrict__ W1b,
                             const float* __restrict__ W2,
                             const float* __restrict__ W2b,
                             float* __restrict__ qq,
                             float* __restrict__ w2t) {
    int u = threadIdx.x;           // 128 threads
    int blk = blockIdx.x;
    if (blk < Bn) {
        int b = blk;
        float acc = W1b[u] + W2b[u];
        #pragma unroll 8
        for (int d = 0; d < DDEC; ++d)
            acc = fmaf(dec[b * DDEC + d], W1[d * Un + u], acc);
        qq[b * Un + u] = acc;
    } else {
        for (int d = 0; d < DENC; ++d)
            w2t[u * DENC + d] = W2[d * Un + u];
    }
}

// Main: per thread = one (b,s) row. enc row (32 x float4 = 128 VGPR) stays
// register-resident: __launch_bounds__(256,2) gives the allocator a 256-VGPR
// budget (the (256,3) cap of ~168 made the compiler sink the row loads into
// the u-loop -> 128x re-load from L1 -> 43% VALUBusy, 557us).
__global__ __launch_bounds__(256, 2)
void score_kernel(const float* __restrict__ enc,    // [B,S,DENC]
                  const float* __restrict__ mask,   // [B,S]
                  const float* __restrict__ qq,     // [B,U]
                  const float* __restrict__ w2t,    // [U,DENC] u-major
                  const float* __restrict__ V,      // [U]
                  const float* __restrict__ Vb,     // [1]
                  float* __restrict__ logits) {     // [B,S]
    int row = blockIdx.x * 256 + threadIdx.x;       // 0..B*S-1
    int b = row >> 13;                              // S = 8192

    // Load this row's 512 B of enc into registers.
    const float4* erow = (const float4*)(enc + (size_t)row * DENC);
    float4 e[32];
    #pragma unroll
    for (int j = 0; j < 32; ++j) e[j] = erow[j];

    const float* qrow = qq + b * Un;
    float score = Vb[0];

    #pragma unroll 1
    for (int u = 0; u < Un; ++u) {
        const float4* w = (const float4*)(w2t + u * DENC);  // wave-uniform -> s_load
        // 4 independent partial accumulators: break the serially-dependent
        // fma chain (4-cyc dep latency vs 2-cyc issue) so 2 waves/SIMD
        // sustain full fp32 issue rate.
        float k0 = qrow[u], k1 = 0.0f, k2 = 0.0f, k3 = 0.0f;
        #pragma unroll
        for (int j = 0; j < 32; j += 4) {
            float4 w0 = w[j], w1 = w[j+1], w2 = w[j+2], w3 = w[j+3];
            k0 = fmaf(e[j  ].x, w0.x, k0); k0 = fmaf(e[j  ].y, w0.y, k0);
            k0 = fmaf(e[j  ].z, w0.z, k0); k0 = fmaf(e[j  ].w, w0.w, k0);
            k1 = fmaf(e[j+1].x, w1.x, k1); k1 = fmaf(e[j+1].y, w1.y, k1);
            k1 = fmaf(e[j+1].z, w1.z, k1); k1 = fmaf(e[j+1].w, w1.w, k1);
            k2 = fmaf(e[j+2].x, w2.x, k2); k2 = fmaf(e[j+2].y, w2.y, k2);
            k2 = fmaf(e[j+2].z, w2.z, k2); k2 = fmaf(e[j+2].w, w2.w, k2);
            k3 = fmaf(e[j+3].x, w3.x, k3); k3 = fmaf(e[j+3].y, w3.y, k3);
            k3 = fmaf(e[j+3].z, w3.z, k3); k3 = fmaf(e[j+3].w, w3.w, k3);
        }
        float k = (k0 + k1) + (k2 + k3);
        score = fmaf(fast_tanh(k), V[u], score);
    }

    float logit = 10.0f * fast_tanh(score) - mask[row] * 1e9f;
    logits[row] = logit;
}

// Softmax + argmax + gather, one block per b.
__global__ __launch_bounds__(256)
void softmax_kernel(const float* __restrict__ logits,  // [B,S]
                    const float* __restrict__ enc_in,  // [B,S,F]
                    float* __restrict__ probs,         // [B,S]
                    float* __restrict__ out_idx,       // [B] (written as float)
                    float* __restrict__ out_gath) {    // [B,F]
    int b = blockIdx.x, tid = threadIdx.x;
    __shared__ float smax[256];
    __shared__ int   sidx[256];
    __shared__ float ssum[256];

    const float* lrow = logits + (size_t)b * Sn;
    float* prow = probs + (size_t)b * Sn;

    // Pass 1: max + first-occurrence argmax
    float bestv = -INFINITY; int besti = 0x7fffffff;
    for (int s = tid; s < Sn; s += 256) {
        float v = lrow[s];
        if (v > bestv) { bestv = v; besti = s; }
    }
    smax[tid] = bestv; sidx[tid] = besti;
    __syncthreads();
    for (int off = 128; off > 0; off >>= 1) {
        if (tid < off) {
            float ov = smax[tid + off]; int oi = sidx[tid + off];
            if (ov > smax[tid] || (ov == smax[tid] && oi < sidx[tid])) {
                smax[tid] = ov; sidx[tid] = oi;
            }
        }
        __syncthreads();
    }
    float M = smax[0]; int I = sidx[0];

    // Pass 2: exp into probs + partial sums
    float psum = 0.0f;
    for (int s = tid; s < Sn; s += 256) {
        float ev = __expf(lrow[s] - M);
        prow[s] = ev;
        psum += ev;
    }
    ssum[tid] = psum;
    __syncthreads();
    for (int off = 128; off > 0; off >>= 1) {
        if (tid < off) ssum[tid] += ssum[tid + off];
        __syncthreads();
    }
    float inv = 1.0f / ssum[0];

    // Pass 3: scale stored exp
    for (int s = tid; s < Sn; s += 256)
        prow[s] *= inv;

    // Index (numeric value as float32) + gather
    if (tid == 0) out_idx[b] = (float)I;
    if (tid < Fn) out_gath[b * Fn + tid] = enc_in[((size_t)b * Sn + I) * Fn + tid];
}

extern "C" void kernel_launch(void* const* d_in, const int* in_sizes, int n_in,
                              void* d_out, int out_size, void* d_ws, size_t ws_size,
                              hipStream_t stream) {
    const float* dec    = (const float*)d_in[0];  // [B,1,DDEC]
    const float* enc_in = (const float*)d_in[1];  // [B,S,F]
    const float* enc    = (const float*)d_in[2];  // [B,S,DENC]
    const float* mask   = (const float*)d_in[3];  // [B,S]
    const float* W1     = (const float*)d_in[4];  // [DDEC,U]
    const float* W1b    = (const float*)d_in[5];  // [U]
    const float* W2     = (const float*)d_in[6];  // [DENC,U]
    const float* W2b    = (const float*)d_in[7];  // [U]
    const float* V      = (const float*)d_in[8];  // [U,1]
    const float* Vb     = (const float*)d_in[9];  // [1]

    float* qq  = (float*)d_ws;          // B*U floats
    float* w2t = qq + Bn * Un;          // U*DENC floats

    float* logits = (float*)d_out;                  // [B,S]
    float* probs  = logits + (size_t)Bn * Sn;       // [B,S]
    float* oidx   = probs + (size_t)Bn * Sn;        // [B]
    float* ogath  = oidx + Bn;                      // [B,F]

    setup_kernel<<<Bn + 1, 128, 0, stream>>>(dec, W1, W1b, W2, W2b, qq, w2t);
    score_kernel<<<(Bn * Sn) / 256, 256, 0, stream>>>(enc, mask, qq, w2t, V, Vb, logits);
    softmax_kernel<<<Bn, 256, 0, stream>>>(logits, enc_in, probs, oidx, ogath);
}